// Round 6
// baseline (523.843 us; speedup 1.0000x reference)
//
#include <hip/hip_runtime.h>

typedef unsigned short u16;
typedef __bf16 bf16x8 __attribute__((ext_vector_type(8)));
typedef float f32x4 __attribute__((ext_vector_type(4)));

#define S_LEN 2048
#define NHEADS 16
#define HD 64
#define HDIM 1024
#define QKVN 3072
#define KAUG 9216   // 1024 (silu) + 1024*8 (spline bases)

__device__ __forceinline__ u16 f2bf(float f) {
  union { float f; unsigned u; } v; v.f = f;
  unsigned r = v.u + 0x7fffu + ((v.u >> 16) & 1u);   // RNE
  return (u16)(r >> 16);
}

typedef __attribute__((address_space(1))) const unsigned int gas_u32;
typedef __attribute__((address_space(3))) unsigned int las_u32;
__device__ __forceinline__ void gload_lds16(const void* g, void* l) {
  __builtin_amdgcn_global_load_lds((gas_u32*)g, (las_u32*)l, 16, 0, 0);
}

// ---------------- prep A: silu(x) and cubic b-spline bases, bf16 ----------------
__global__ void prep_a_kernel(const float* __restrict__ x, u16* __restrict__ Aaug) {
  int idx = blockIdx.x * 256 + threadIdx.x;     // 2048*1024 threads
  int n = idx >> 10, i = idx & 1023;
  float xv = x[idx];
  float sil = xv / (1.0f + __expf(-xv));
  Aaug[(size_t)n * KAUG + i] = f2bf(sil);

  float b[11];
#pragma unroll
  for (int j = 0; j < 11; ++j) {
    float t0 = 0.4f * (float)(j - 3) - 1.0f;
    float t1 = 0.4f * (float)(j - 2) - 1.0f;
    b[j] = (xv >= t0 && xv < t1) ? 1.0f : 0.0f;
  }
  // recurrence with constant reciprocals (denominators are 0.4*k): no fdiv
#pragma unroll
  for (int k = 1; k <= 3; ++k) {
    const float invk = (k == 1) ? 2.5f : (k == 2) ? 1.25f : 0.83333333f;
#pragma unroll
    for (int j = 0; j < 10; ++j) {
      if (j + k < 11) {
        float tj   = 0.4f * (float)(j - 3) - 1.0f;
        float tjk1 = 0.4f * (float)(j + k - 2) - 1.0f;
        b[j] = ((xv - tj) * b[j] + (tjk1 - xv) * b[j + 1]) * invk;
      }
    }
  }
  u16 t[8];
#pragma unroll
  for (int j = 0; j < 8; ++j) t[j] = f2bf(b[j]);
  uint4 pk;
  pk.x = (unsigned)t[0] | ((unsigned)t[1] << 16);
  pk.y = (unsigned)t[2] | ((unsigned)t[3] << 16);
  pk.z = (unsigned)t[4] | ((unsigned)t[5] << 16);
  pk.w = (unsigned)t[6] | ((unsigned)t[7] << 16);
  *reinterpret_cast<uint4*>(&Aaug[(size_t)n * KAUG + 1024 + i * 8]) = pk;
}

// ---------------- prep W: [base_w | spline_w*scaler] bf16 ----------------
__global__ void prep_w_kernel(const float* __restrict__ bw, const float* __restrict__ sw,
                              const float* __restrict__ sc, u16* __restrict__ Waug) {
  int idx = blockIdx.x * 256 + threadIdx.x;     // 3072*1024 threads
  int o = idx >> 10, i = idx & 1023;
  Waug[(size_t)o * KAUG + i] = f2bf(bw[idx]);
  float s = sc[idx];
  const float4* sp = reinterpret_cast<const float4*>(sw + (size_t)idx * 8);
  float4 a = sp[0], b = sp[1];
  uint4 pk;
  pk.x = (unsigned)f2bf(a.x * s) | ((unsigned)f2bf(a.y * s) << 16);
  pk.y = (unsigned)f2bf(a.z * s) | ((unsigned)f2bf(a.w * s) << 16);
  pk.z = (unsigned)f2bf(b.x * s) | ((unsigned)f2bf(b.y * s) << 16);
  pk.w = (unsigned)f2bf(b.z * s) | ((unsigned)f2bf(b.w * s) << 16);
  *reinterpret_cast<uint4*>(&Waug[(size_t)o * KAUG + 1024 + i * 8]) = pk;
}

// ---------------- prep out_w -> bf16 ----------------
__global__ void prep_ow_kernel(const float* __restrict__ ow, u16* __restrict__ owbf) {
  int idx = blockIdx.x * 256 + threadIdx.x;     // 1024*1024/4 threads
  float4 v = reinterpret_cast<const float4*>(ow)[idx];
  uint2 pk;
  pk.x = (unsigned)f2bf(v.x) | ((unsigned)f2bf(v.y) << 16);
  pk.y = (unsigned)f2bf(v.z) | ((unsigned)f2bf(v.w) << 16);
  reinterpret_cast<uint2*>(owbf)[idx] = pk;
}

// ---------- GEMM: C[z][M,N] = A[M, kz] * B[N, kz]^T, bf16 MFMA, split-K via z ----------
// Measured-good structure: BK=32, 16KB LDS, 128x128 tile, 4 waves (r3: 650 TF @3 blk/CU).
__global__ __launch_bounds__(256) void gemm_bt(
    const u16* __restrict__ A, const u16* __restrict__ B, float* __restrict__ C,
    int M, int N, int K, int Ksp)
{
  __shared__ u16 As[128 * 32];
  __shared__ u16 Bs[128 * 32];
  const int tid = threadIdx.x;
  const int lane = tid & 63;
  const int w = tid >> 6;
  const int wr = w >> 1, wc = w & 1;
  const int row0 = blockIdx.y * 128, col0 = blockIdx.x * 128;
  const int lr = lane & 15, lg = lane >> 4;
  const int kbeg = blockIdx.z * Ksp;
  const int nsteps = Ksp >> 5;
  float* Cz = C + (size_t)blockIdx.z * M * N;

  f32x4 acc[4][4];
#pragma unroll
  for (int m = 0; m < 4; ++m)
#pragma unroll
    for (int n = 0; n < 4; ++n) acc[m][n] = (f32x4){0.f, 0.f, 0.f, 0.f};

  const int arow = tid >> 2;      // 0..63
  const int kch  = tid & 3;       // 0..3, 8 bf16 each
  const u16* ga = A + (size_t)(row0 + arow) * K + kbeg + kch * 8;
  const u16* gb = B + (size_t)(col0 + arow) * K + kbeg + kch * 8;
  const size_t rstep = (size_t)64 * K;

  for (int ks = 0; ks < nsteps; ++ks) {
    gload_lds16(ga, &As[tid * 8]);
    gload_lds16(ga + rstep, &As[2048 + tid * 8]);
    gload_lds16(gb, &Bs[tid * 8]);
    gload_lds16(gb + rstep, &Bs[2048 + tid * 8]);
    ga += 32; gb += 32;
    __syncthreads();

    bf16x8 af[4], bf[4];
#pragma unroll
    for (int m = 0; m < 4; ++m) {
      int r = wr * 64 + m * 16 + lr;
      af[m] = *reinterpret_cast<const bf16x8*>(&As[r * 32 + lg * 8]);
    }
#pragma unroll
    for (int n = 0; n < 4; ++n) {
      int r = wc * 64 + n * 16 + lr;
      bf[n] = *reinterpret_cast<const bf16x8*>(&Bs[r * 32 + lg * 8]);
    }
#pragma unroll
    for (int m = 0; m < 4; ++m)
#pragma unroll
      for (int n = 0; n < 4; ++n)
        acc[m][n] = __builtin_amdgcn_mfma_f32_16x16x32_bf16(af[m], bf[n], acc[m][n], 0, 0, 0);
    __syncthreads();
  }

#pragma unroll
  for (int m = 0; m < 4; ++m) {
    int row = row0 + wr * 64 + m * 16 + lg * 4;
#pragma unroll
    for (int n = 0; n < 4; ++n) {
      int col = col0 + wc * 64 + n * 16 + lr;
#pragma unroll
      for (int j = 0; j < 4; ++j)
        Cz[(size_t)(row + j) * N + col] = acc[m][n][j];
    }
  }
}

// ---------------- reduce 4 split-K partials + bias (float4) ----------------
__global__ void reduce4_bias_kernel(const float* __restrict__ p, const float* __restrict__ bias,
                                    float* __restrict__ out) {
  int idx = blockIdx.x * 256 + threadIdx.x;     // 2048*1024/4
  const float4* p4 = reinterpret_cast<const float4*>(p);
  const size_t stride4 = (size_t)2048 * 1024 / 4;
  float4 a = p4[idx], b = p4[idx + stride4], c = p4[idx + 2 * stride4], d = p4[idx + 3 * stride4];
  float4 bv = reinterpret_cast<const float4*>(bias)[idx & 255];
  float4 r;
  r.x = a.x + b.x + c.x + d.x + bv.x;
  r.y = a.y + b.y + c.y + d.y + bv.y;
  r.z = a.z + b.z + c.z + d.z + bv.z;
  r.w = a.w + b.w + c.w + d.w + bv.w;
  reinterpret_cast<float4*>(out)[idx] = r;
}

// ------- RoPE on q,k (sums nsplit split-K partials); per-head bf16, q scaled 1/8 -------
__global__ void rope_kernel(const float* __restrict__ qkv, int nsplit,
                            const float* __restrict__ rc, const float* __restrict__ rs,
                            u16* __restrict__ qro, u16* __restrict__ kro) {
  int idx = blockIdx.x * 256 + threadIdx.x;   // 16*2048*32
  int h = idx >> 16;
  int rem = idx & 65535;
  int s = rem >> 5, i = rem & 31;
  size_t boff = (size_t)s * QKVN + h * 192 + 2 * i;
  const size_t zstr = (size_t)S_LEN * QKVN;
  float q0 = 0.f, q1 = 0.f, k0 = 0.f, k1 = 0.f;
  for (int z = 0; z < nsplit; ++z) {
    const float* b = qkv + z * zstr + boff;
    float2 qv = *reinterpret_cast<const float2*>(b);
    float2 kv = *reinterpret_cast<const float2*>(b + 64);
    q0 += qv.x; q1 += qv.y; k0 += kv.x; k1 += kv.y;
  }
  float c = rc[s * 32 + i], sn = rs[s * 32 + i];
  size_t ob = ((size_t)(h * S_LEN + s)) * HD + 2 * i;
  unsigned qpk = (unsigned)f2bf((q0 * c - q1 * sn) * 0.125f) |
                 ((unsigned)f2bf((q0 * sn + q1 * c) * 0.125f) << 16);
  unsigned kpk = (unsigned)f2bf(k0 * c - k1 * sn) |
                 ((unsigned)f2bf(k0 * sn + k1 * c) << 16);
  *reinterpret_cast<unsigned*>(qro + ob) = qpk;
  *reinterpret_cast<unsigned*>(kro + ob) = kpk;
}

// ------------ V transpose (sums nsplit partials): vT[h][d][s] bf16 ------------
__global__ void vtrans_kernel(const float* __restrict__ qkv, int nsplit,
                              u16* __restrict__ vT) {
  __shared__ float tile[64][65];
  int h = blockIdx.x >> 5;
  int st = blockIdx.x & 31;
  int s0 = st * 64;
  int t = threadIdx.x;
  int r = t >> 2, c4 = t & 3;
  size_t soff = (size_t)(s0 + r) * QKVN + h * 192 + 128 + c4 * 16;
  const size_t zstr = (size_t)S_LEN * QKVN;
#pragma unroll
  for (int z4 = 0; z4 < 4; ++z4) {
    float acc4[4] = {0.f, 0.f, 0.f, 0.f};
    for (int z = 0; z < nsplit; ++z) {
      float4 v = *reinterpret_cast<const float4*>(qkv + z * zstr + soff + z4 * 4);
      acc4[0] += v.x; acc4[1] += v.y; acc4[2] += v.z; acc4[3] += v.w;
    }
    tile[r][c4 * 16 + z4 * 4 + 0] = acc4[0];
    tile[r][c4 * 16 + z4 * 4 + 1] = acc4[1];
    tile[r][c4 * 16 + z4 * 4 + 2] = acc4[2];
    tile[r][c4 * 16 + z4 * 4 + 3] = acc4[3];
  }
  __syncthreads();
  int d = t >> 2, sc = t & 3;
  u16* dst = vT + ((size_t)(h * 64 + d)) * S_LEN + s0 + sc * 16;
  unsigned wv[8];
#pragma unroll
  for (int z = 0; z < 8; ++z) {
    unsigned lo = f2bf(tile[sc * 16 + 2 * z][d]);
    unsigned hi = f2bf(tile[sc * 16 + 2 * z + 1][d]);
    wv[z] = lo | (hi << 16);
  }
  *reinterpret_cast<uint4*>(dst)     = make_uint4(wv[0], wv[1], wv[2], wv[3]);
  *reinterpret_cast<uint4*>(dst + 8) = make_uint4(wv[4], wv[5], wv[6], wv[7]);
}

// ---- flash attention: swapped QK^T, in-register softmax/P-exchange, K/V prefetch ----
// Per wave: 16 q-rows. Lane (lr,lg) owns q-row lr. Per iter: issue V(this tile) and
// K(next tile) loads FIRST so L2 latency hides under QK^T+softmax (vmcnt counting
// lets kc-use wait only on the previous iteration's loads).
__global__ __launch_bounds__(256) void attn_kernel(
    const u16* __restrict__ qro, const u16* __restrict__ kro,
    const u16* __restrict__ vT, u16* __restrict__ ctxb)
{
  const int lane = threadIdx.x & 63;
  const int w = threadIdx.x >> 6;
  // XCD-chunked remap: same-head blocks land on the same XCD (K/V L2 locality)
  const int bid = (blockIdx.x & 7) * 64 + (blockIdx.x >> 3);   // 512 blocks, bijective
  const int h = bid >> 5;
  const int qt = (bid & 31) * 4 + w;     // 0..127
  const int lr = lane & 15, lg = lane >> 4;

  const u16* qbase = qro + ((size_t)(h * S_LEN + qt * 16 + lr)) * HD + lg * 8;
  bf16x8 qa0 = *reinterpret_cast<const bf16x8*>(qbase);
  bf16x8 qa1 = *reinterpret_cast<const bf16x8*>(qbase + 32);

  float mrow = -3.0e38f, lrow = 0.f;
  f32x4 o[4];
#pragma unroll
  for (int n = 0; n < 4; ++n) o[n] = (f32x4){0.f, 0.f, 0.f, 0.f};

  const int sA = lr + 32 * (lg & 1);   // P-exchange source lanes
  const int sB = sA + 16;
  const bool loHalf = (lg < 2);

  const u16* kbase = kro + ((size_t)(h * S_LEN + lr)) * HD + lg * 8;
  const u16* vbase = vT + ((size_t)(h * 64 + lr)) * S_LEN + lg * 8;

  // preload K tile 0
  bf16x8 kc00 = *reinterpret_cast<const bf16x8*>(kbase);
  bf16x8 kc01 = *reinterpret_cast<const bf16x8*>(kbase + 32);
  bf16x8 kc10 = *reinterpret_cast<const bf16x8*>(kbase + 16 * HD);
  bf16x8 kc11 = *reinterpret_cast<const bf16x8*>(kbase + 16 * HD + 32);

  for (int kt = 0; kt < 64; ++kt) {
    // V loads for this tile (used at the end of the iteration)
    const u16* vb = vbase + kt * 32;
    bf16x8 vf0 = *reinterpret_cast<const bf16x8*>(vb);
    bf16x8 vf1 = *reinterpret_cast<const bf16x8*>(vb + (size_t)16 * S_LEN);
    bf16x8 vf2 = *reinterpret_cast<const bf16x8*>(vb + (size_t)32 * S_LEN);
    bf16x8 vf3 = *reinterpret_cast<const bf16x8*>(vb + (size_t)48 * S_LEN);
    // next K tile (wraps to 0 at the end; unused then)
    const u16* knb = kbase + (size_t)(((kt + 1) & 63) * 32) * HD;
    bf16x8 kn00 = *reinterpret_cast<const bf16x8*>(knb);
    bf16x8 kn01 = *reinterpret_cast<const bf16x8*>(knb + 32);
    bf16x8 kn10 = *reinterpret_cast<const bf16x8*>(knb + 16 * HD);
    bf16x8 kn11 = *reinterpret_cast<const bf16x8*>(knb + 16 * HD + 32);

    // swapped QK^T: s0[j] = S[key0+4lg+j][q=lr], s1[j] = S[key0+16+4lg+j][q=lr]
    f32x4 s0 = (f32x4){0.f, 0.f, 0.f, 0.f};
    f32x4 s1 = (f32x4){0.f, 0.f, 0.f, 0.f};
    __builtin_amdgcn_s_setprio(1);
    s0 = __builtin_amdgcn_mfma_f32_16x16x32_bf16(kc00, qa0, s0, 0, 0, 0);
    s0 = __builtin_amdgcn_mfma_f32_16x16x32_bf16(kc01, qa1, s0, 0, 0, 0);
    s1 = __builtin_amdgcn_mfma_f32_16x16x32_bf16(kc10, qa0, s1, 0, 0, 0);
    s1 = __builtin_amdgcn_mfma_f32_16x16x32_bf16(kc11, qa1, s1, 0, 0, 0);
    __builtin_amdgcn_s_setprio(0);

    // row max over this lane's 8 keys, then across the 4 lg-groups of this q-row
    float vmax = fmaxf(fmaxf(fmaxf(s0[0], s0[1]), fmaxf(s0[2], s0[3])),
                       fmaxf(fmaxf(s1[0], s1[1]), fmaxf(s1[2], s1[3])));
    vmax = fmaxf(vmax, __shfl_xor(vmax, 16));
    vmax = fmaxf(vmax, __shfl_xor(vmax, 32));

    if (__any(vmax > mrow + 8.0f)) {       // defer-max: rare rescale
      float mnew = fmaxf(mrow, vmax);
      float al = __expf(mrow - mnew);
      float alO[4];
#pragma unroll
      for (int j = 0; j < 4; ++j) alO[j] = __shfl(al, lg * 4 + j);
#pragma unroll
      for (int n = 0; n < 4; ++n)
#pragma unroll
        for (int j = 0; j < 4; ++j) o[n][j] *= alO[j];
      lrow *= al;
      mrow = mnew;
    }

    float p[8];
#pragma unroll
    for (int j = 0; j < 4; ++j) {
      p[j]     = __expf(s0[j] - mrow);
      p[4 + j] = __expf(s1[j] - mrow);
    }
    lrow += ((p[0] + p[1]) + (p[2] + p[3])) + ((p[4] + p[5]) + (p[6] + p[7]));

    // pack to bf16: {keys 4lg..+3, keys 16+4lg..+3}
    union { bf16x8 v; uint4 u; } pk_;
#pragma unroll
    for (int j = 0; j < 8; ++j) pk_.v[j] = (__bf16)p[j];

    // exchange: dest lane needs keys 8lg..8lg+7 of its q-row
    unsigned a0 = __shfl((int)pk_.u.x, sA), a1 = __shfl((int)pk_.u.y, sA);
    unsigned a2 = __shfl((int)pk_.u.x, sB), a3 = __shfl((int)pk_.u.y, sB);
    unsigned b0 = __shfl((int)pk_.u.z, sA), b1 = __shfl((int)pk_.u.w, sA);
    unsigned b2 = __shfl((int)pk_.u.z, sB), b3 = __shfl((int)pk_.u.w, sB);
    union { uint4 u; bf16x8 v; } pa_;
    pa_.u.x = loHalf ? a0 : b0;
    pa_.u.y = loHalf ? a1 : b1;
    pa_.u.z = loHalf ? a2 : b2;
    pa_.u.w = loHalf ? a3 : b3;

    __builtin_amdgcn_s_setprio(1);
    o[0] = __builtin_amdgcn_mfma_f32_16x16x32_bf16(pa_.v, vf0, o[0], 0, 0, 0);
    o[1] = __builtin_amdgcn_mfma_f32_16x16x32_bf16(pa_.v, vf1, o[1], 0, 0, 0);
    o[2] = __builtin_amdgcn_mfma_f32_16x16x32_bf16(pa_.v, vf2, o[2], 0, 0, 0);
    o[3] = __builtin_amdgcn_mfma_f32_16x16x32_bf16(pa_.v, vf3, o[3], 0, 0, 0);
    __builtin_amdgcn_s_setprio(0);

    kc00 = kn00; kc01 = kn01; kc10 = kn10; kc11 = kn11;
  }

  // finish denominator: sum the 4 lg-partials of each q-row
  lrow += __shfl_xor(lrow, 16);
  lrow += __shfl_xor(lrow, 32);
  float linv[4];
#pragma unroll
  for (int j = 0; j < 4; ++j) linv[j] = 1.0f / __shfl(lrow, lg * 4 + j);

#pragma unroll
  for (int n = 0; n < 4; ++n) {
    int col = h * 64 + n * 16 + lr;
#pragma unroll
    for (int j = 0; j < 4; ++j) {
      int row = qt * 16 + lg * 4 + j;
      ctxb[(size_t)row * HDIM + col] = f2bf(o[n][j] * linv[j]);
    }
  }
}

extern "C" void kernel_launch(void* const* d_in, const int* in_sizes, int n_in,
                              void* d_out, int out_size, void* d_ws, size_t ws_size,
                              hipStream_t stream) {
  const float* x   = (const float*)d_in[0];
  const float* bw  = (const float*)d_in[1];
  const float* sw  = (const float*)d_in[2];
  const float* ssc = (const float*)d_in[3];
  const float* ow  = (const float*)d_in[4];
  const float* ob  = (const float*)d_in[5];
  const float* rc  = (const float*)d_in[6];
  const float* rs  = (const float*)d_in[7];
  float* out = (float*)d_out;

  char* ws = (char*)d_ws;
  const size_t MNF = 25165824;                      // one qkv partial (2048*3072*4)
  // split-K=4 needs 209,715,200 B of workspace; fall back to 2 if unavailable.
  const int splitk = (ws_size >= (size_t)209715200) ? 4 : 2;

  u16*   Aaug  = (u16*)(ws);                        // 37,748,736
  u16*   Waug  = (u16*)(ws + 37748736);             // 56,623,104
  float* qkv   = (float*)(ws + 94371840);           // splitk * 25,165,824
  size_t qend  = 94371840 + (size_t)splitk * MNF;
  u16*   qro   = (u16*)(ws + qend);                 // 4,194,304
  u16*   kro   = (u16*)(ws + qend + 4194304);       // 4,194,304
  u16*   vT    = (u16*)(ws + qend + 8388608);       // 4,194,304
  u16*   owbf  = (u16*)(ws + qend + 12582912);      // 2,097,152
  u16*   ctxb  = (u16*)(ws + 94371840);             // aliases qkv partial 0 (dead)
  float* part  = (float*)(ws + 94371840 + MNF);     // gemm2 partials over dead qkv1..

  prep_a_kernel<<<8192, 256, 0, stream>>>(x, Aaug);
  prep_w_kernel<<<12288, 256, 0, stream>>>(bw, sw, ssc, Waug);
  prep_ow_kernel<<<1024, 256, 0, stream>>>(ow, owbf);

  // KAN-linear GEMM: split-K -> splitk*384 blocks (4 -> 6 blocks/CU resident)
  gemm_bt<<<dim3(24, 16, splitk), 256, 0, stream>>>(Aaug, Waug, qkv, 2048, 3072, 9216,
                                                    9216 / splitk);

  rope_kernel<<<4096, 256, 0, stream>>>(qkv, splitk, rc, rs, qro, kro);
  vtrans_kernel<<<512, 256, 0, stream>>>(qkv, splitk, vT);

  attn_kernel<<<512, 256, 0, stream>>>(qro, kro, vT, ctxb);

  // output projection, split-K=4 (512 blocks), then fused reduce+bias
  gemm_bt<<<dim3(8, 16, 4), 256, 0, stream>>>(ctxb, owbf, part, 2048, 1024, 1024, 256);
  reduce4_bias_kernel<<<2048, 256, 0, stream>>>(part, ob, out);
}

// Round 7
// 506.177 us; speedup vs baseline: 1.0349x; 1.0349x over previous
//
#include <hip/hip_runtime.h>

typedef unsigned short u16;
typedef __bf16 bf16x8 __attribute__((ext_vector_type(8)));
typedef float f32x4 __attribute__((ext_vector_type(4)));

#define S_LEN 2048
#define NHEADS 16
#define HD 64
#define HDIM 1024
#define QKVN 3072
#define KAUG 9216   // 1024 (silu) + 1024*8 (spline bases)

__device__ __forceinline__ u16 f2bf(float f) {
  union { float f; unsigned u; } v; v.f = f;
  unsigned r = v.u + 0x7fffu + ((v.u >> 16) & 1u);   // RNE
  return (u16)(r >> 16);
}

typedef __attribute__((address_space(1))) const unsigned int gas_u32;
typedef __attribute__((address_space(3))) unsigned int las_u32;
__device__ __forceinline__ void gload_lds16(const void* g, void* l) {
  __builtin_amdgcn_global_load_lds((gas_u32*)g, (las_u32*)l, 16, 0, 0);
}

// ---------------- prep A: silu(x) and cubic b-spline bases, bf16 ----------------
__global__ void prep_a_kernel(const float* __restrict__ x, u16* __restrict__ Aaug) {
  int idx = blockIdx.x * 256 + threadIdx.x;     // 2048*1024 threads
  int n = idx >> 10, i = idx & 1023;
  float xv = x[idx];
  float sil = xv / (1.0f + __expf(-xv));
  Aaug[(size_t)n * KAUG + i] = f2bf(sil);

  float b[11];
#pragma unroll
  for (int j = 0; j < 11; ++j) {
    float t0 = 0.4f * (float)(j - 3) - 1.0f;
    float t1 = 0.4f * (float)(j - 2) - 1.0f;
    b[j] = (xv >= t0 && xv < t1) ? 1.0f : 0.0f;
  }
  // recurrence with constant reciprocals (denominators are 0.4*k): no fdiv
#pragma unroll
  for (int k = 1; k <= 3; ++k) {
    const float invk = (k == 1) ? 2.5f : (k == 2) ? 1.25f : 0.83333333f;
#pragma unroll
    for (int j = 0; j < 10; ++j) {
      if (j + k < 11) {
        float tj   = 0.4f * (float)(j - 3) - 1.0f;
        float tjk1 = 0.4f * (float)(j + k - 2) - 1.0f;
        b[j] = ((xv - tj) * b[j] + (tjk1 - xv) * b[j + 1]) * invk;
      }
    }
  }
  u16 t[8];
#pragma unroll
  for (int j = 0; j < 8; ++j) t[j] = f2bf(b[j]);
  uint4 pk;
  pk.x = (unsigned)t[0] | ((unsigned)t[1] << 16);
  pk.y = (unsigned)t[2] | ((unsigned)t[3] << 16);
  pk.z = (unsigned)t[4] | ((unsigned)t[5] << 16);
  pk.w = (unsigned)t[6] | ((unsigned)t[7] << 16);
  *reinterpret_cast<uint4*>(&Aaug[(size_t)n * KAUG + 1024 + i * 8]) = pk;
}

// ---------------- prep W: [base_w | spline_w*scaler] bf16 ----------------
__global__ void prep_w_kernel(const float* __restrict__ bw, const float* __restrict__ sw,
                              const float* __restrict__ sc, u16* __restrict__ Waug) {
  int idx = blockIdx.x * 256 + threadIdx.x;     // 3072*1024 threads
  int o = idx >> 10, i = idx & 1023;
  Waug[(size_t)o * KAUG + i] = f2bf(bw[idx]);
  float s = sc[idx];
  const float4* sp = reinterpret_cast<const float4*>(sw + (size_t)idx * 8);
  float4 a = sp[0], b = sp[1];
  uint4 pk;
  pk.x = (unsigned)f2bf(a.x * s) | ((unsigned)f2bf(a.y * s) << 16);
  pk.y = (unsigned)f2bf(a.z * s) | ((unsigned)f2bf(a.w * s) << 16);
  pk.z = (unsigned)f2bf(b.x * s) | ((unsigned)f2bf(b.y * s) << 16);
  pk.w = (unsigned)f2bf(b.z * s) | ((unsigned)f2bf(b.w * s) << 16);
  *reinterpret_cast<uint4*>(&Waug[(size_t)o * KAUG + 1024 + i * 8]) = pk;
}

// ---------------- prep out_w -> bf16 ----------------
__global__ void prep_ow_kernel(const float* __restrict__ ow, u16* __restrict__ owbf) {
  int idx = blockIdx.x * 256 + threadIdx.x;     // 1024*1024/4 threads
  float4 v = reinterpret_cast<const float4*>(ow)[idx];
  uint2 pk;
  pk.x = (unsigned)f2bf(v.x) | ((unsigned)f2bf(v.y) << 16);
  pk.y = (unsigned)f2bf(v.z) | ((unsigned)f2bf(v.w) << 16);
  reinterpret_cast<uint2*>(owbf)[idx] = pk;
}

// ---------- GEMM: C[z][M,N] = A[M, kz] * B[N, kz]^T, bf16 MFMA, split-K via z ----------
// BK=32, 16KB LDS (measured-good residency: 3 blocks/CU, reg-limited).
// Chunk XOR-swizzle kills the 8-way ds_read_b128 bank conflict: the 4x16B chunks of
// each 64B row are stored at slot = chunk ^ ((row>>1)&3). global_load_lds keeps a
// LINEAR dest; the per-lane GLOBAL source chunk is pre-XORed (both-sides rule);
// sw(row)==sw(row+64) so one XOR serves both staged halves. Read slot = lg ^ ((lr>>1)&3)
// is m-independent -> computed once, zero loop cost. Result: 2-way aliasing (free).
__global__ __launch_bounds__(256) void gemm_bt(
    const u16* __restrict__ A, const u16* __restrict__ B, float* __restrict__ C,
    int M, int N, int K, int Ksp)
{
  __shared__ u16 As[128 * 32];
  __shared__ u16 Bs[128 * 32];
  const int tid = threadIdx.x;
  const int lane = tid & 63;
  const int w = tid >> 6;
  const int wr = w >> 1, wc = w & 1;
  const int row0 = blockIdx.y * 128, col0 = blockIdx.x * 128;
  const int lr = lane & 15, lg = lane >> 4;
  const int kbeg = blockIdx.z * Ksp;
  const int nsteps = Ksp >> 5;
  float* Cz = C + (size_t)blockIdx.z * M * N;

  f32x4 acc[4][4];
#pragma unroll
  for (int m = 0; m < 4; ++m)
#pragma unroll
    for (int n = 0; n < 4; ++n) acc[m][n] = (f32x4){0.f, 0.f, 0.f, 0.f};

  const int srow = tid >> 2;                        // 0..63
  const int kch  = (tid & 3) ^ ((srow >> 1) & 3);   // pre-swizzled source chunk
  const u16* ga = A + (size_t)(row0 + srow) * K + kbeg + kch * 8;
  const u16* gb = B + (size_t)(col0 + srow) * K + kbeg + kch * 8;
  const size_t rstep = (size_t)64 * K;

  const int slotx = (lg ^ ((lr >> 1) & 3)) * 8;     // read-side swizzled slot (u16)

  for (int ks = 0; ks < nsteps; ++ks) {
    gload_lds16(ga, &As[tid * 8]);
    gload_lds16(ga + rstep, &As[2048 + tid * 8]);
    gload_lds16(gb, &Bs[tid * 8]);
    gload_lds16(gb + rstep, &Bs[2048 + tid * 8]);
    ga += 32; gb += 32;
    __syncthreads();

    bf16x8 af[4], bf[4];
#pragma unroll
    for (int m = 0; m < 4; ++m) {
      int r = wr * 64 + m * 16 + lr;
      af[m] = *reinterpret_cast<const bf16x8*>(&As[r * 32 + slotx]);
    }
#pragma unroll
    for (int n = 0; n < 4; ++n) {
      int r = wc * 64 + n * 16 + lr;
      bf[n] = *reinterpret_cast<const bf16x8*>(&Bs[r * 32 + slotx]);
    }
#pragma unroll
    for (int m = 0; m < 4; ++m)
#pragma unroll
      for (int n = 0; n < 4; ++n)
        acc[m][n] = __builtin_amdgcn_mfma_f32_16x16x32_bf16(af[m], bf[n], acc[m][n], 0, 0, 0);
    __syncthreads();
  }

#pragma unroll
  for (int m = 0; m < 4; ++m) {
    int row = row0 + wr * 64 + m * 16 + lg * 4;
#pragma unroll
    for (int n = 0; n < 4; ++n) {
      int col = col0 + wc * 64 + n * 16 + lr;
#pragma unroll
      for (int j = 0; j < 4; ++j)
        Cz[(size_t)(row + j) * N + col] = acc[m][n][j];
    }
  }
}

// ---------------- reduce 4 split-K partials + bias (float4) ----------------
__global__ void reduce4_bias_kernel(const float* __restrict__ p, const float* __restrict__ bias,
                                    float* __restrict__ out) {
  int idx = blockIdx.x * 256 + threadIdx.x;     // 2048*1024/4
  const float4* p4 = reinterpret_cast<const float4*>(p);
  const size_t stride4 = (size_t)2048 * 1024 / 4;
  float4 a = p4[idx], b = p4[idx + stride4], c = p4[idx + 2 * stride4], d = p4[idx + 3 * stride4];
  float4 bv = reinterpret_cast<const float4*>(bias)[idx & 255];
  float4 r;
  r.x = a.x + b.x + c.x + d.x + bv.x;
  r.y = a.y + b.y + c.y + d.y + bv.y;
  r.z = a.z + b.z + c.z + d.z + bv.z;
  r.w = a.w + b.w + c.w + d.w + bv.w;
  reinterpret_cast<float4*>(out)[idx] = r;
}

// ------- RoPE on q,k (sums nsplit split-K partials); per-head bf16, q scaled 1/8 -------
__global__ void rope_kernel(const float* __restrict__ qkv, int nsplit,
                            const float* __restrict__ rc, const float* __restrict__ rs,
                            u16* __restrict__ qro, u16* __restrict__ kro) {
  int idx = blockIdx.x * 256 + threadIdx.x;   // 16*2048*32
  int h = idx >> 16;
  int rem = idx & 65535;
  int s = rem >> 5, i = rem & 31;
  size_t boff = (size_t)s * QKVN + h * 192 + 2 * i;
  const size_t zstr = (size_t)S_LEN * QKVN;
  float q0 = 0.f, q1 = 0.f, k0 = 0.f, k1 = 0.f;
  for (int z = 0; z < nsplit; ++z) {
    const float* b = qkv + z * zstr + boff;
    float2 qv = *reinterpret_cast<const float2*>(b);
    float2 kv = *reinterpret_cast<const float2*>(b + 64);
    q0 += qv.x; q1 += qv.y; k0 += kv.x; k1 += kv.y;
  }
  float c = rc[s * 32 + i], sn = rs[s * 32 + i];
  size_t ob = ((size_t)(h * S_LEN + s)) * HD + 2 * i;
  unsigned qpk = (unsigned)f2bf((q0 * c - q1 * sn) * 0.125f) |
                 ((unsigned)f2bf((q0 * sn + q1 * c) * 0.125f) << 16);
  unsigned kpk = (unsigned)f2bf(k0 * c - k1 * sn) |
                 ((unsigned)f2bf(k0 * sn + k1 * c) << 16);
  *reinterpret_cast<unsigned*>(qro + ob) = qpk;
  *reinterpret_cast<unsigned*>(kro + ob) = kpk;
}

// ------------ V transpose (sums nsplit partials): vT[h][d][s] bf16 ------------
__global__ void vtrans_kernel(const float* __restrict__ qkv, int nsplit,
                              u16* __restrict__ vT) {
  __shared__ float tile[64][65];
  int h = blockIdx.x >> 5;
  int st = blockIdx.x & 31;
  int s0 = st * 64;
  int t = threadIdx.x;
  int r = t >> 2, c4 = t & 3;
  size_t soff = (size_t)(s0 + r) * QKVN + h * 192 + 128 + c4 * 16;
  const size_t zstr = (size_t)S_LEN * QKVN;
#pragma unroll
  for (int z4 = 0; z4 < 4; ++z4) {
    float acc4[4] = {0.f, 0.f, 0.f, 0.f};
    for (int z = 0; z < nsplit; ++z) {
      float4 v = *reinterpret_cast<const float4*>(qkv + z * zstr + soff + z4 * 4);
      acc4[0] += v.x; acc4[1] += v.y; acc4[2] += v.z; acc4[3] += v.w;
    }
    tile[r][c4 * 16 + z4 * 4 + 0] = acc4[0];
    tile[r][c4 * 16 + z4 * 4 + 1] = acc4[1];
    tile[r][c4 * 16 + z4 * 4 + 2] = acc4[2];
    tile[r][c4 * 16 + z4 * 4 + 3] = acc4[3];
  }
  __syncthreads();
  int d = t >> 2, sc = t & 3;
  u16* dst = vT + ((size_t)(h * 64 + d)) * S_LEN + s0 + sc * 16;
  unsigned wv[8];
#pragma unroll
  for (int z = 0; z < 8; ++z) {
    unsigned lo = f2bf(tile[sc * 16 + 2 * z][d]);
    unsigned hi = f2bf(tile[sc * 16 + 2 * z + 1][d]);
    wv[z] = lo | (hi << 16);
  }
  *reinterpret_cast<uint4*>(dst)     = make_uint4(wv[0], wv[1], wv[2], wv[3]);
  *reinterpret_cast<uint4*>(dst + 8) = make_uint4(wv[4], wv[5], wv[6], wv[7]);
}

// ---- flash attention: swapped QK^T, in-register softmax/P-exchange, K/V prefetch ----
__global__ __launch_bounds__(256) void attn_kernel(
    const u16* __restrict__ qro, const u16* __restrict__ kro,
    const u16* __restrict__ vT, u16* __restrict__ ctxb)
{
  const int lane = threadIdx.x & 63;
  const int w = threadIdx.x >> 6;
  // XCD-chunked remap: same-head blocks land on the same XCD (K/V L2 locality)
  const int bid = (blockIdx.x & 7) * 64 + (blockIdx.x >> 3);   // 512 blocks, bijective
  const int h = bid >> 5;
  const int qt = (bid & 31) * 4 + w;     // 0..127
  const int lr = lane & 15, lg = lane >> 4;

  const u16* qbase = qro + ((size_t)(h * S_LEN + qt * 16 + lr)) * HD + lg * 8;
  bf16x8 qa0 = *reinterpret_cast<const bf16x8*>(qbase);
  bf16x8 qa1 = *reinterpret_cast<const bf16x8*>(qbase + 32);

  float mrow = -3.0e38f, lrow = 0.f;
  f32x4 o[4];
#pragma unroll
  for (int n = 0; n < 4; ++n) o[n] = (f32x4){0.f, 0.f, 0.f, 0.f};

  const int sA = lr + 32 * (lg & 1);   // P-exchange source lanes
  const int sB = sA + 16;
  const bool loHalf = (lg < 2);

  const u16* kbase = kro + ((size_t)(h * S_LEN + lr)) * HD + lg * 8;
  const u16* vbase = vT + ((size_t)(h * 64 + lr)) * S_LEN + lg * 8;

  // preload K tile 0
  bf16x8 kc00 = *reinterpret_cast<const bf16x8*>(kbase);
  bf16x8 kc01 = *reinterpret_cast<const bf16x8*>(kbase + 32);
  bf16x8 kc10 = *reinterpret_cast<const bf16x8*>(kbase + 16 * HD);
  bf16x8 kc11 = *reinterpret_cast<const bf16x8*>(kbase + 16 * HD + 32);

  for (int kt = 0; kt < 64; ++kt) {
    // V loads for this tile (used at the end of the iteration)
    const u16* vb = vbase + kt * 32;
    bf16x8 vf0 = *reinterpret_cast<const bf16x8*>(vb);
    bf16x8 vf1 = *reinterpret_cast<const bf16x8*>(vb + (size_t)16 * S_LEN);
    bf16x8 vf2 = *reinterpret_cast<const bf16x8*>(vb + (size_t)32 * S_LEN);
    bf16x8 vf3 = *reinterpret_cast<const bf16x8*>(vb + (size_t)48 * S_LEN);
    // next K tile (wraps to 0 at the end; unused then)
    const u16* knb = kbase + (size_t)(((kt + 1) & 63) * 32) * HD;
    bf16x8 kn00 = *reinterpret_cast<const bf16x8*>(knb);
    bf16x8 kn01 = *reinterpret_cast<const bf16x8*>(knb + 32);
    bf16x8 kn10 = *reinterpret_cast<const bf16x8*>(knb + 16 * HD);
    bf16x8 kn11 = *reinterpret_cast<const bf16x8*>(knb + 16 * HD + 32);

    // swapped QK^T: s0[j] = S[key0+4lg+j][q=lr], s1[j] = S[key0+16+4lg+j][q=lr]
    f32x4 s0 = (f32x4){0.f, 0.f, 0.f, 0.f};
    f32x4 s1 = (f32x4){0.f, 0.f, 0.f, 0.f};
    __builtin_amdgcn_s_setprio(1);
    s0 = __builtin_amdgcn_mfma_f32_16x16x32_bf16(kc00, qa0, s0, 0, 0, 0);
    s0 = __builtin_amdgcn_mfma_f32_16x16x32_bf16(kc01, qa1, s0, 0, 0, 0);
    s1 = __builtin_amdgcn_mfma_f32_16x16x32_bf16(kc10, qa0, s1, 0, 0, 0);
    s1 = __builtin_amdgcn_mfma_f32_16x16x32_bf16(kc11, qa1, s1, 0, 0, 0);
    __builtin_amdgcn_s_setprio(0);

    // row max over this lane's 8 keys, then across the 4 lg-groups of this q-row
    float vmax = fmaxf(fmaxf(fmaxf(s0[0], s0[1]), fmaxf(s0[2], s0[3])),
                       fmaxf(fmaxf(s1[0], s1[1]), fmaxf(s1[2], s1[3])));
    vmax = fmaxf(vmax, __shfl_xor(vmax, 16));
    vmax = fmaxf(vmax, __shfl_xor(vmax, 32));

    if (__any(vmax > mrow + 8.0f)) {       // defer-max: rare rescale
      float mnew = fmaxf(mrow, vmax);
      float al = __expf(mrow - mnew);
      float alO[4];
#pragma unroll
      for (int j = 0; j < 4; ++j) alO[j] = __shfl(al, lg * 4 + j);
#pragma unroll
      for (int n = 0; n < 4; ++n)
#pragma unroll
        for (int j = 0; j < 4; ++j) o[n][j] *= alO[j];
      lrow *= al;
      mrow = mnew;
    }

    float p[8];
#pragma unroll
    for (int j = 0; j < 4; ++j) {
      p[j]     = __expf(s0[j] - mrow);
      p[4 + j] = __expf(s1[j] - mrow);
    }
    lrow += ((p[0] + p[1]) + (p[2] + p[3])) + ((p[4] + p[5]) + (p[6] + p[7]));

    // pack to bf16: {keys 4lg..+3, keys 16+4lg..+3}
    union { bf16x8 v; uint4 u; } pk_;
#pragma unroll
    for (int j = 0; j < 8; ++j) pk_.v[j] = (__bf16)p[j];

    // exchange: dest lane needs keys 8lg..8lg+7 of its q-row
    unsigned a0 = __shfl((int)pk_.u.x, sA), a1 = __shfl((int)pk_.u.y, sA);
    unsigned a2 = __shfl((int)pk_.u.x, sB), a3 = __shfl((int)pk_.u.y, sB);
    unsigned b0 = __shfl((int)pk_.u.z, sA), b1 = __shfl((int)pk_.u.w, sA);
    unsigned b2 = __shfl((int)pk_.u.z, sB), b3 = __shfl((int)pk_.u.w, sB);
    union { uint4 u; bf16x8 v; } pa_;
    pa_.u.x = loHalf ? a0 : b0;
    pa_.u.y = loHalf ? a1 : b1;
    pa_.u.z = loHalf ? a2 : b2;
    pa_.u.w = loHalf ? a3 : b3;

    __builtin_amdgcn_s_setprio(1);
    o[0] = __builtin_amdgcn_mfma_f32_16x16x32_bf16(pa_.v, vf0, o[0], 0, 0, 0);
    o[1] = __builtin_amdgcn_mfma_f32_16x16x32_bf16(pa_.v, vf1, o[1], 0, 0, 0);
    o[2] = __builtin_amdgcn_mfma_f32_16x16x32_bf16(pa_.v, vf2, o[2], 0, 0, 0);
    o[3] = __builtin_amdgcn_mfma_f32_16x16x32_bf16(pa_.v, vf3, o[3], 0, 0, 0);
    __builtin_amdgcn_s_setprio(0);

    kc00 = kn00; kc01 = kn01; kc10 = kn10; kc11 = kn11;
  }

  // finish denominator: sum the 4 lg-partials of each q-row
  lrow += __shfl_xor(lrow, 16);
  lrow += __shfl_xor(lrow, 32);
  float linv[4];
#pragma unroll
  for (int j = 0; j < 4; ++j) linv[j] = 1.0f / __shfl(lrow, lg * 4 + j);

#pragma unroll
  for (int n = 0; n < 4; ++n) {
    int col = h * 64 + n * 16 + lr;
#pragma unroll
    for (int j = 0; j < 4; ++j) {
      int row = qt * 16 + lg * 4 + j;
      ctxb[(size_t)row * HDIM + col] = f2bf(o[n][j] * linv[j]);
    }
  }
}

extern "C" void kernel_launch(void* const* d_in, const int* in_sizes, int n_in,
                              void* d_out, int out_size, void* d_ws, size_t ws_size,
                              hipStream_t stream) {
  const float* x   = (const float*)d_in[0];
  const float* bw  = (const float*)d_in[1];
  const float* sw  = (const float*)d_in[2];
  const float* ssc = (const float*)d_in[3];
  const float* ow  = (const float*)d_in[4];
  const float* ob  = (const float*)d_in[5];
  const float* rc  = (const float*)d_in[6];
  const float* rs  = (const float*)d_in[7];
  float* out = (float*)d_out;

  char* ws = (char*)d_ws;
  const size_t MNF = 25165824;                      // one qkv partial (2048*3072*4)
  const int splitk = 2;                             // r6: splitk=4 == splitk=2 (reg-capped)

  u16*   Aaug  = (u16*)(ws);                        // 37,748,736
  u16*   Waug  = (u16*)(ws + 37748736);             // 56,623,104
  float* qkv   = (float*)(ws + 94371840);           // 2 * 25,165,824
  size_t qend  = 94371840 + (size_t)splitk * MNF;   // 144,703,488
  u16*   qro   = (u16*)(ws + qend);                 // 4,194,304
  u16*   kro   = (u16*)(ws + qend + 4194304);       // 4,194,304
  u16*   vT    = (u16*)(ws + qend + 8388608);       // 4,194,304
  u16*   owbf  = (u16*)(ws + qend + 12582912);      // 2,097,152
  u16*   ctxb  = (u16*)(ws + 94371840);             // aliases qkv partial 0 (dead)
  // gemm2 partials (33.5MB) over dead qkv partial 1 + qro + kro; ends at vT.
  float* part  = (float*)(ws + 94371840 + MNF);

  prep_a_kernel<<<8192, 256, 0, stream>>>(x, Aaug);
  prep_w_kernel<<<12288, 256, 0, stream>>>(bw, sw, ssc, Waug);
  prep_ow_kernel<<<1024, 256, 0, stream>>>(ow, owbf);

  // KAN-linear GEMM, split-K=2: 768 blocks (3 blocks/CU, register-capped)
  gemm_bt<<<dim3(24, 16, splitk), 256, 0, stream>>>(Aaug, Waug, qkv, 2048, 3072, 9216,
                                                    9216 / splitk);

  rope_kernel<<<4096, 256, 0, stream>>>(qkv, splitk, rc, rs, qro, kro);
  vtrans_kernel<<<512, 256, 0, stream>>>(qkv, splitk, vT);

  attn_kernel<<<512, 256, 0, stream>>>(qro, kro, vT, ctxb);

  // output projection, split-K=4 (512 blocks), then fused reduce+bias
  gemm_bt<<<dim3(8, 16, 4), 256, 0, stream>>>(ctxb, owbf, part, 2048, 1024, 1024, 256);
  reduce4_bias_kernel<<<2048, 256, 0, stream>>>(part, ob, out);
}